// Round 1
// baseline (612.294 us; speedup 1.0000x reference)
//
#include <hip/hip_runtime.h>

#define NN 50000
#define NE 400000

// ---------------- degree / norm ----------------
__global__ void deg_init_kernel(float* __restrict__ deg) {
    int i = blockIdx.x * blockDim.x + threadIdx.x;
    if (i < NN) deg[i] = 1.0f;  // self loop
}

__global__ void deg_count_kernel(const int* __restrict__ dst, float* __restrict__ deg) {
    for (int e = blockIdx.x * blockDim.x + threadIdx.x; e < NE; e += gridDim.x * blockDim.x)
        atomicAdd(&deg[dst[e]], 1.0f);
}

__global__ void dinv_kernel(float* __restrict__ deg) {
    int i = blockIdx.x * blockDim.x + threadIdx.x;
    if (i < NN) deg[i] = rsqrtf(deg[i]);  // deg >= 1 always
}

// ---------------- aggregation ----------------
// out[i*C+c] = h[i*C+c] * dinv[i]^2   (self-loop contribution, initializes out)
template <int C>
__global__ void self_init_kernel(const float* __restrict__ h, const float* __restrict__ dinv,
                                 float* __restrict__ out) {
    long total = (long)NN * C;
    for (long idx = blockIdx.x * (long)blockDim.x + threadIdx.x; idx < total;
         idx += (long)gridDim.x * blockDim.x) {
        int i = (int)(idx / C);
        float w = dinv[i];
        out[idx] = h[idx] * w * w;
    }
}

// one wave per edge: out[dst] += h[src] * dinv[src]*dinv[dst]
template <int C>
__global__ void agg_edge_kernel(const int* __restrict__ src, const int* __restrict__ dst,
                                const float* __restrict__ dinv, const float* __restrict__ h,
                                float* __restrict__ out) {
    int lane = threadIdx.x & 63;
    int wave = blockIdx.x * (blockDim.x >> 6) + (threadIdx.x >> 6);
    int nwaves = gridDim.x * (blockDim.x >> 6);
    for (int e = wave; e < NE; e += nwaves) {
        int s = src[e], d = dst[e];
        float w = dinv[s] * dinv[d];
        #pragma unroll
        for (int c = lane; c < C; c += 64)
            atomicAdd(&out[(long)d * C + c], h[(long)s * C + c] * w);
    }
}

// in-place h = relu(h + b), C = 64
__global__ void bias_relu64_kernel(float* __restrict__ h, const float* __restrict__ b) {
    long total = (long)NN * 64;
    for (long idx = blockIdx.x * (long)blockDim.x + threadIdx.x; idx < total;
         idx += (long)gridDim.x * blockDim.x) {
        int c = (int)(idx & 63);
        float v = h[idx] + b[c];
        h[idx] = v > 0.0f ? v : 0.0f;
    }
}

// ---------------- final (mu | logstd) layer ----------------
// out layout: mu = out[0 .. NN*32), logstd = out[NN*32 .. NN*64)
__global__ void final_init_kernel(const float* __restrict__ h, const float* __restrict__ dinv,
                                  const float* __restrict__ bmu, const float* __restrict__ bls,
                                  float* __restrict__ out) {
    long total = (long)NN * 64;
    for (long idx = blockIdx.x * (long)blockDim.x + threadIdx.x; idx < total;
         idx += (long)gridDim.x * blockDim.x) {
        int i = (int)(idx >> 6);
        int c = (int)(idx & 63);
        float w = dinv[i];
        float v = h[idx] * w * w;
        if (c < 32)
            out[(long)i * 32 + c] = v + bmu[c];
        else
            out[(long)NN * 32 + (long)i * 32 + (c - 32)] = v + bls[c - 32];
    }
}

__global__ void final_agg_kernel(const int* __restrict__ src, const int* __restrict__ dst,
                                 const float* __restrict__ dinv, const float* __restrict__ h,
                                 float* __restrict__ out) {
    int lane = threadIdx.x & 63;
    int wave = blockIdx.x * (blockDim.x >> 6) + (threadIdx.x >> 6);
    int nwaves = gridDim.x * (blockDim.x >> 6);
    for (int e = wave; e < NE; e += nwaves) {
        int s = src[e], d = dst[e];
        float w = dinv[s] * dinv[d];
        float v = h[(long)s * 64 + lane] * w;
        if (lane < 32)
            atomicAdd(&out[(long)d * 32 + lane], v);
        else
            atomicAdd(&out[(long)NN * 32 + (long)d * 32 + (lane - 32)], v);
    }
}

// concat Wmu [64,32] and Wls [64,32] -> Wcat [64,64]
__global__ void wcat_kernel(const float* __restrict__ Wmu, const float* __restrict__ Wls,
                            float* __restrict__ Wcat) {
    int idx = blockIdx.x * blockDim.x + threadIdx.x;
    if (idx < 64 * 64) {
        int k = idx >> 6, c = idx & 63;
        Wcat[idx] = (c < 32) ? Wmu[k * 32 + c] : Wls[k * 32 + (c - 32)];
    }
}

// ---------------- GEMM: C[M,N] = A[M,K] @ B[K,N] (+bias, relu) ----------------
template <bool RELU_BIAS>
__global__ __launch_bounds__(256) void gemm_kernel(const float* __restrict__ A,
                                                   const float* __restrict__ B,
                                                   const float* __restrict__ bias,
                                                   float* __restrict__ C, int M, int N, int K) {
    const int BK = 16;
    __shared__ float As[BK][65];  // [k][m]
    __shared__ float Bs[BK][65];  // [k][n]
    int tid = threadIdx.x;
    int bm0 = blockIdx.x * 64;
    int bn0 = blockIdx.y * 64;
    int m0 = (tid >> 4) * 4;
    int n0 = (tid & 15) * 4;
    float acc[4][4] = {};
    for (int k0 = 0; k0 < K; k0 += BK) {
        for (int i = tid; i < 64 * BK; i += 256) {
            int m = i >> 4, k = i & 15;
            int gm = bm0 + m, gk = k0 + k;
            As[k][m] = (gm < M && gk < K) ? A[(long)gm * K + gk] : 0.0f;
        }
        for (int i = tid; i < BK * 64; i += 256) {
            int k = i >> 6, n = i & 63;
            int gk = k0 + k, gn = bn0 + n;
            Bs[k][n] = (gk < K && gn < N) ? B[(long)gk * N + gn] : 0.0f;
        }
        __syncthreads();
        #pragma unroll
        for (int k = 0; k < BK; ++k) {
            float a[4], b[4];
            #pragma unroll
            for (int i = 0; i < 4; ++i) a[i] = As[k][m0 + i];
            #pragma unroll
            for (int j = 0; j < 4; ++j) b[j] = Bs[k][n0 + j];
            #pragma unroll
            for (int i = 0; i < 4; ++i)
                #pragma unroll
                for (int j = 0; j < 4; ++j) acc[i][j] = fmaf(a[i], b[j], acc[i][j]);
        }
        __syncthreads();
    }
    for (int i = 0; i < 4; ++i) {
        int gm = bm0 + m0 + i;
        if (gm >= M) break;
        #pragma unroll
        for (int j = 0; j < 4; ++j) {
            int gn = bn0 + n0 + j;
            if (gn >= N) continue;
            float v = acc[i][j];
            if (RELU_BIAS) {
                v += bias[gn];
                v = v > 0.0f ? v : 0.0f;
            }
            C[(long)gm * N + gn] = v;
        }
    }
}

extern "C" void kernel_launch(void* const* d_in, const int* in_sizes, int n_in,
                              void* d_out, int out_size, void* d_ws, size_t ws_size,
                              hipStream_t stream) {
    const float* x   = (const float*)d_in[0];
    const int*   ei  = (const int*)d_in[1];
    const int*   src = ei;         // edge_index[0]
    const int*   dst = ei + NE;    // edge_index[1]
    const float* W1  = (const float*)d_in[2];
    const float* b1  = (const float*)d_in[3];
    const float* W2  = (const float*)d_in[4];
    const float* b2  = (const float*)d_in[5];
    const float* Wmu = (const float*)d_in[6];
    const float* bmu = (const float*)d_in[7];
    const float* Wls = (const float*)d_in[8];
    const float* bls = (const float*)d_in[9];
    float* out = (float*)d_out;

    float* ws   = (float*)d_ws;
    float* dinv = ws;                    // 50,048
    float* xa   = dinv + 50048;          // 50000*109 -> 5,450,240 (reused as h3p)
    float* h1   = xa + 5450240;          // 50000*320 = 16,000,000
    float* h2p  = h1 + 16000000;         // 3,200,000
    float* h2   = h2p + 3200000;         // 3,200,000
    float* wcat = h2 + 3200000;          // 4096

    const int TB = 256;
    int nb_nodes = (NN + TB - 1) / TB;

    // norm
    deg_init_kernel<<<nb_nodes, TB, 0, stream>>>(dinv);
    deg_count_kernel<<<1024, TB, 0, stream>>>(dst, dinv);
    dinv_kernel<<<nb_nodes, TB, 0, stream>>>(dinv);

    // layer 1: xa = agg(x); h1 = relu(xa @ W1 + b1)
    self_init_kernel<109><<<2048, TB, 0, stream>>>(x, dinv, xa);
    agg_edge_kernel<109><<<4096, TB, 0, stream>>>(src, dst, dinv, x, xa);
    gemm_kernel<true><<<dim3(782, 5), 256, 0, stream>>>(xa, W1, b1, h1, NN, 320, 109);

    // layer 2: h2p = h1 @ W2; h2 = relu(agg(h2p) + b2)
    gemm_kernel<false><<<dim3(782, 1), 256, 0, stream>>>(h1, W2, nullptr, h2p, NN, 64, 320);
    self_init_kernel<64><<<2048, TB, 0, stream>>>(h2p, dinv, h2);
    agg_edge_kernel<64><<<4096, TB, 0, stream>>>(src, dst, dinv, h2p, h2);
    bias_relu64_kernel<<<2048, TB, 0, stream>>>(h2, b2);

    // layers 3+4 fused: h3p = h2 @ [Wmu|Wls]; out = agg(h3p) + [bmu|bls]
    wcat_kernel<<<16, 256, 0, stream>>>(Wmu, Wls, wcat);
    gemm_kernel<false><<<dim3(782, 1), 256, 0, stream>>>(h2, wcat, nullptr, xa, NN, 64, 64);
    final_init_kernel<<<2048, TB, 0, stream>>>(xa, dinv, bmu, bls, out);
    final_agg_kernel<<<4096, TB, 0, stream>>>(src, dst, dinv, xa, out);
}

// Round 2
// 418.921 us; speedup vs baseline: 1.4616x; 1.4616x over previous
//
#include <hip/hip_runtime.h>

#define NN 50000
#define NE 400000

// ---------------- degree / hist ----------------
__global__ void zero_int_kernel(int* __restrict__ p, int n) {
    int i = blockIdx.x * blockDim.x + threadIdx.x;
    if (i < n) p[i] = 0;
}

__global__ void hist_kernel(const int* __restrict__ dst, int* __restrict__ counts) {
    for (int e = blockIdx.x * blockDim.x + threadIdx.x; e < NE; e += gridDim.x * blockDim.x)
        atomicAdd(&counts[dst[e]], 1);
}

__global__ void dinv_kernel(const int* __restrict__ counts, float* __restrict__ dinv) {
    int i = blockIdx.x * blockDim.x + threadIdx.x;
    if (i < NN) dinv[i] = rsqrtf((float)(counts[i] + 1));  // +1 self loop
}

// ---------------- exclusive scan over counts -> rowstart ----------------
__global__ void scan1_kernel(const int* __restrict__ counts, int* __restrict__ rowstart,
                             int* __restrict__ bsum) {
    __shared__ int tmp[256];
    int tid = threadIdx.x;
    int i = blockIdx.x * 256 + tid;
    int v = (i < NN) ? counts[i] : 0;
    tmp[tid] = v;
    __syncthreads();
    for (int off = 1; off < 256; off <<= 1) {
        int t = 0;
        if (tid >= off) t = tmp[tid - off];
        __syncthreads();
        if (tid >= off) tmp[tid] += t;
        __syncthreads();
    }
    if (i < NN) rowstart[i] = tmp[tid] - v;  // exclusive
    if (tid == 255) bsum[blockIdx.x] = tmp[255];
}

__global__ void scan2_kernel(int* __restrict__ bsum, int nb) {
    __shared__ int tmp[256];
    int tid = threadIdx.x;
    int v = (tid < nb) ? bsum[tid] : 0;
    tmp[tid] = v;
    __syncthreads();
    for (int off = 1; off < 256; off <<= 1) {
        int t = 0;
        if (tid >= off) t = tmp[tid - off];
        __syncthreads();
        if (tid >= off) tmp[tid] += t;
        __syncthreads();
    }
    if (tid < nb) bsum[tid] = tmp[tid] - v;  // exclusive
}

__global__ void scan3_kernel(int* __restrict__ rowstart, const int* __restrict__ bsum) {
    int i = blockIdx.x * 256 + threadIdx.x;
    if (i < NN) rowstart[i] += bsum[blockIdx.x];
    if (i == 0) rowstart[NN] = NE;
}

__global__ void scatter_kernel(const int* __restrict__ src, const int* __restrict__ dst,
                               const int* __restrict__ rowstart, int* __restrict__ cursor,
                               int* __restrict__ esrc) {
    for (int e = blockIdx.x * blockDim.x + threadIdx.x; e < NE; e += gridDim.x * blockDim.x) {
        int d = dst[e];
        int pos = rowstart[d] + atomicAdd(&cursor[d], 1);
        esrc[pos] = src[e];
    }
}

// ---------------- prescale: g = x * dinv[row]  (C=109) ----------------
__global__ void prescale109_kernel(const float* __restrict__ x, const float* __restrict__ dinv,
                                   float* __restrict__ g) {
    long total = (long)NN * 109;
    for (long idx = blockIdx.x * (long)blockDim.x + threadIdx.x; idx < total;
         idx += (long)gridDim.x * blockDim.x) {
        int i = (int)(idx / 109);
        g[idx] = x[idx] * dinv[i];
    }
}

// ---------------- CSR aggregation: out[d] = dinv[d] * (g[d] + sum g[src]) ----------------
// C = 109: lane handles c=lane and c=lane+64 (store-guarded)
__global__ __launch_bounds__(256) void agg109_kernel(const int* __restrict__ rowstart,
                                                     const int* __restrict__ esrc,
                                                     const float* __restrict__ dinv,
                                                     const float* __restrict__ g,
                                                     float* __restrict__ out) {
    int wave = blockIdx.x * (blockDim.x >> 6) + (threadIdx.x >> 6);
    if (wave >= NN) return;
    int lane = threadIdx.x & 63;
    long base = (long)wave * 109;
    float acc0 = g[base + lane];
    float acc1 = g[base + 64 + lane];  // lanes >=45 read pad/next row; discarded at store
    int j0 = rowstart[wave], j1 = rowstart[wave + 1];
    for (int j = j0; j < j1; ++j) {
        long sb = (long)esrc[j] * 109;
        acc0 += g[sb + lane];
        acc1 += g[sb + 64 + lane];
    }
    float w = dinv[wave];
    out[base + lane] = acc0 * w;
    if (lane < 45) out[base + 64 + lane] = acc1 * w;
}

// C = 64, epilogue: relu(v * dinv + b)
__global__ __launch_bounds__(256) void agg64_relu_kernel(const int* __restrict__ rowstart,
                                                         const int* __restrict__ esrc,
                                                         const float* __restrict__ dinv,
                                                         const float* __restrict__ g,
                                                         const float* __restrict__ b,
                                                         float* __restrict__ out) {
    int wave = blockIdx.x * (blockDim.x >> 6) + (threadIdx.x >> 6);
    if (wave >= NN) return;
    int lane = threadIdx.x & 63;
    long base = (long)wave * 64;
    float acc = g[base + lane];
    int j0 = rowstart[wave], j1 = rowstart[wave + 1];
    for (int j = j0; j < j1; ++j) acc += g[(long)esrc[j] * 64 + lane];
    float v = acc * dinv[wave] + b[lane];
    out[base + lane] = v > 0.0f ? v : 0.0f;
}

// C = 64, final: split into mu / logstd halves of d_out, + bias
__global__ __launch_bounds__(256) void agg64_final_kernel(const int* __restrict__ rowstart,
                                                          const int* __restrict__ esrc,
                                                          const float* __restrict__ dinv,
                                                          const float* __restrict__ g,
                                                          const float* __restrict__ bmu,
                                                          const float* __restrict__ bls,
                                                          float* __restrict__ out) {
    int wave = blockIdx.x * (blockDim.x >> 6) + (threadIdx.x >> 6);
    if (wave >= NN) return;
    int lane = threadIdx.x & 63;
    long base = (long)wave * 64;
    float acc = g[base + lane];
    int j0 = rowstart[wave], j1 = rowstart[wave + 1];
    for (int j = j0; j < j1; ++j) acc += g[(long)esrc[j] * 64 + lane];
    float v = acc * dinv[wave];
    if (lane < 32)
        out[(long)wave * 32 + lane] = v + bmu[lane];
    else
        out[(long)NN * 32 + (long)wave * 32 + (lane - 32)] = v + bls[lane - 32];
}

// concat Wmu [64,32] | Wls [64,32] -> Wcat [64,64]
__global__ void wcat_kernel(const float* __restrict__ Wmu, const float* __restrict__ Wls,
                            float* __restrict__ Wcat) {
    int idx = blockIdx.x * blockDim.x + threadIdx.x;
    if (idx < 64 * 64) {
        int k = idx >> 6, c = idx & 63;
        Wcat[idx] = (c < 32) ? Wmu[k * 32 + c] : Wls[k * 32 + (c - 32)];
    }
}

// ---------------- GEMM: C[M,N] = A[M,K] @ B[K,N] (+bias+relu | *dinv[row]) ----------------
template <bool RELU_BIAS, bool ROW_SCALE>
__global__ __launch_bounds__(256) void gemm_kernel(const float* __restrict__ A,
                                                   const float* __restrict__ B,
                                                   const float* __restrict__ bias,
                                                   const float* __restrict__ dinv,
                                                   float* __restrict__ C, int M, int N, int K) {
    const int BK = 16;
    __shared__ float As[BK][65];  // [k][m]
    __shared__ float Bs[BK][65];  // [k][n]
    int tid = threadIdx.x;
    int bm0 = blockIdx.x * 64;
    int bn0 = blockIdx.y * 64;
    int m0 = (tid >> 4) * 4;
    int n0 = (tid & 15) * 4;
    float acc[4][4] = {};
    for (int k0 = 0; k0 < K; k0 += BK) {
        for (int i = tid; i < 64 * BK; i += 256) {
            int m = i >> 4, k = i & 15;
            int gm = bm0 + m, gk = k0 + k;
            As[k][m] = (gm < M && gk < K) ? A[(long)gm * K + gk] : 0.0f;
        }
        for (int i = tid; i < BK * 64; i += 256) {
            int k = i >> 6, n = i & 63;
            int gk = k0 + k, gn = bn0 + n;
            Bs[k][n] = (gk < K && gn < N) ? B[(long)gk * N + gn] : 0.0f;
        }
        __syncthreads();
        #pragma unroll
        for (int k = 0; k < BK; ++k) {
            float a[4], b[4];
            #pragma unroll
            for (int i = 0; i < 4; ++i) a[i] = As[k][m0 + i];
            #pragma unroll
            for (int j = 0; j < 4; ++j) b[j] = Bs[k][n0 + j];
            #pragma unroll
            for (int i = 0; i < 4; ++i)
                #pragma unroll
                for (int j = 0; j < 4; ++j) acc[i][j] = fmaf(a[i], b[j], acc[i][j]);
        }
        __syncthreads();
    }
    for (int i = 0; i < 4; ++i) {
        int gm = bm0 + m0 + i;
        if (gm >= M) break;
        float rs = ROW_SCALE ? dinv[gm] : 1.0f;
        #pragma unroll
        for (int j = 0; j < 4; ++j) {
            int gn = bn0 + n0 + j;
            if (gn >= N) continue;
            float v = acc[i][j];
            if (RELU_BIAS) {
                v += bias[gn];
                v = v > 0.0f ? v : 0.0f;
            }
            if (ROW_SCALE) v *= rs;
            C[(long)gm * N + gn] = v;
        }
    }
}

extern "C" void kernel_launch(void* const* d_in, const int* in_sizes, int n_in,
                              void* d_out, int out_size, void* d_ws, size_t ws_size,
                              hipStream_t stream) {
    const float* x   = (const float*)d_in[0];
    const int*   ei  = (const int*)d_in[1];
    const int*   src = ei;       // edge_index[0]
    const int*   dst = ei + NE;  // edge_index[1]
    const float* W1  = (const float*)d_in[2];
    const float* b1  = (const float*)d_in[3];
    const float* W2  = (const float*)d_in[4];
    const float* b2  = (const float*)d_in[5];
    const float* Wmu = (const float*)d_in[6];
    const float* bmu = (const float*)d_in[7];
    const float* Wls = (const float*)d_in[8];
    const float* bls = (const float*)d_in[9];
    float* out = (float*)d_out;

    // ---- workspace layout (~110 MB) ----
    char* p = (char*)d_ws;
    float* dinv   = (float*)p; p += 50048 * 4;
    int* counts   = (int*)p;   p += 50048 * 4;
    int* cursor   = (int*)p;   p += 50048 * 4;
    int* rowstart = (int*)p;   p += 50056 * 4;
    int* bsum     = (int*)p;   p += 256 * 4;
    int* esrc     = (int*)p;   p += 400000 * 4;
    float* bufA   = (float*)p; p += 5450240L * 4;  // g1, later h2
    float* bufB   = (float*)p; p += 5450240L * 4;  // xa, later g2, later g3
    float* h1     = (float*)p; p += 16000000L * 4;
    float* wcat   = (float*)p; p += 4096 * 4;

    const int TB = 256;
    const int NB_NODES = (NN + TB - 1) / TB;       // 196
    const int NB_AGG = (NN * 64 + TB - 1) / TB;    // 12500 (wave per node)

    // ---- CSR build ----
    zero_int_kernel<<<(100096 + TB - 1) / TB, TB, 0, stream>>>(counts, 100096);  // counts+cursor
    hist_kernel<<<1024, TB, 0, stream>>>(dst, counts);
    dinv_kernel<<<NB_NODES, TB, 0, stream>>>(counts, dinv);
    scan1_kernel<<<NB_NODES, TB, 0, stream>>>(counts, rowstart, bsum);
    scan2_kernel<<<1, 256, 0, stream>>>(bsum, NB_NODES);
    scan3_kernel<<<NB_NODES, TB, 0, stream>>>(rowstart, bsum);
    scatter_kernel<<<1024, TB, 0, stream>>>(src, dst, rowstart, cursor, esrc);

    // ---- layer 1: g1 = x*dinv; xa = agg(g1); h1 = relu(xa@W1 + b1) ----
    prescale109_kernel<<<2048, TB, 0, stream>>>(x, dinv, bufA);
    agg109_kernel<<<NB_AGG, TB, 0, stream>>>(rowstart, esrc, dinv, bufA, bufB);
    gemm_kernel<true, false><<<dim3(782, 5), 256, 0, stream>>>(bufB, W1, b1, nullptr, h1, NN, 320, 109);

    // ---- layer 2: g2 = (h1@W2)*dinv; h2 = relu(agg(g2) + b2) ----
    gemm_kernel<false, true><<<dim3(782, 1), 256, 0, stream>>>(h1, W2, nullptr, dinv, bufB, NN, 64, 320);
    agg64_relu_kernel<<<NB_AGG, TB, 0, stream>>>(rowstart, esrc, dinv, bufB, b2, bufA);

    // ---- layers 3+4: g3 = (h2@[Wmu|Wls])*dinv; out = agg(g3) + [bmu|bls] ----
    wcat_kernel<<<16, 256, 0, stream>>>(Wmu, Wls, wcat);
    gemm_kernel<false, true><<<dim3(782, 1), 256, 0, stream>>>(bufA, wcat, nullptr, dinv, bufB, NN, 64, 64);
    agg64_final_kernel<<<NB_AGG, TB, 0, stream>>>(rowstart, esrc, dinv, bufB, bmu, bls, out);
}

// Round 3
// 389.493 us; speedup vs baseline: 1.5720x; 1.0756x over previous
//
#include <hip/hip_runtime.h>

#define NN 50000
#define NE 400000

// ---------------- degree / hist ----------------
__global__ void zero_int_kernel(int* __restrict__ p, int n) {
    int i = blockIdx.x * blockDim.x + threadIdx.x;
    if (i < n) p[i] = 0;
}

__global__ void hist_kernel(const int* __restrict__ dst, int* __restrict__ counts) {
    for (int e = blockIdx.x * blockDim.x + threadIdx.x; e < NE; e += gridDim.x * blockDim.x)
        atomicAdd(&counts[dst[e]], 1);
}

__global__ void dinv_kernel(const int* __restrict__ counts, float* __restrict__ dinv) {
    int i = blockIdx.x * blockDim.x + threadIdx.x;
    if (i < NN) dinv[i] = rsqrtf((float)(counts[i] + 1));  // +1 self loop
}

// ---------------- exclusive scan over counts -> rowstart ----------------
__global__ void scan1_kernel(const int* __restrict__ counts, int* __restrict__ rowstart,
                             int* __restrict__ bsum) {
    __shared__ int tmp[256];
    int tid = threadIdx.x;
    int i = blockIdx.x * 256 + tid;
    int v = (i < NN) ? counts[i] : 0;
    tmp[tid] = v;
    __syncthreads();
    for (int off = 1; off < 256; off <<= 1) {
        int t = 0;
        if (tid >= off) t = tmp[tid - off];
        __syncthreads();
        if (tid >= off) tmp[tid] += t;
        __syncthreads();
    }
    if (i < NN) rowstart[i] = tmp[tid] - v;  // exclusive
    if (tid == 255) bsum[blockIdx.x] = tmp[255];
}

__global__ void scan2_kernel(int* __restrict__ bsum, int nb) {
    __shared__ int tmp[256];
    int tid = threadIdx.x;
    int v = (tid < nb) ? bsum[tid] : 0;
    tmp[tid] = v;
    __syncthreads();
    for (int off = 1; off < 256; off <<= 1) {
        int t = 0;
        if (tid >= off) t = tmp[tid - off];
        __syncthreads();
        if (tid >= off) tmp[tid] += t;
        __syncthreads();
    }
    if (tid < nb) bsum[tid] = tmp[tid] - v;  // exclusive
}

__global__ void scan3_kernel(int* __restrict__ rowstart, const int* __restrict__ bsum) {
    int i = blockIdx.x * 256 + threadIdx.x;
    if (i < NN) rowstart[i] += bsum[blockIdx.x];
    if (i == 0) rowstart[NN] = NE;
}

__global__ void scatter_kernel(const int* __restrict__ src, const int* __restrict__ dst,
                               const int* __restrict__ rowstart, int* __restrict__ cursor,
                               int* __restrict__ esrc) {
    for (int e = blockIdx.x * blockDim.x + threadIdx.x; e < NE; e += gridDim.x * blockDim.x) {
        int d = dst[e];
        int pos = rowstart[d] + atomicAdd(&cursor[d], 1);
        esrc[pos] = src[e];
    }
}

// ---------------- CSR aggregation, layer 1 (reads x directly, C=109) ----------------
// out[d] = dinv[d] * ( x[d]*dinv[d] + sum_{s in N(d)} x[s]*dinv[s] )
__global__ __launch_bounds__(256) void agg109_kernel(const int* __restrict__ rowstart,
                                                     const int* __restrict__ esrc,
                                                     const float* __restrict__ dinv,
                                                     const float* __restrict__ x,
                                                     float* __restrict__ out) {
    int wave = blockIdx.x * (blockDim.x >> 6) + (threadIdx.x >> 6);
    if (wave >= NN) return;
    int lane = threadIdx.x & 63;
    long base = (long)wave * 109;
    float wd = dinv[wave];
    float acc0 = x[base + lane] * wd;
    float acc1 = (lane < 45) ? x[base + 64 + lane] * wd : 0.0f;
    int j0 = rowstart[wave], j1 = rowstart[wave + 1];
    for (int j = j0; j < j1; ++j) {
        int s = esrc[j];
        long sb = (long)s * 109;
        float w = dinv[s];
        acc0 += x[sb + lane] * w;
        if (lane < 45) acc1 += x[sb + 64 + lane] * w;
    }
    out[base + lane] = acc0 * wd;
    if (lane < 45) out[base + 64 + lane] = acc1 * wd;
}

// C = 64, epilogue: relu(v * dinv + b)   (g already prescaled by dinv[row])
__global__ __launch_bounds__(256) void agg64_relu_kernel(const int* __restrict__ rowstart,
                                                         const int* __restrict__ esrc,
                                                         const float* __restrict__ dinv,
                                                         const float* __restrict__ g,
                                                         const float* __restrict__ b,
                                                         float* __restrict__ out) {
    int wave = blockIdx.x * (blockDim.x >> 6) + (threadIdx.x >> 6);
    if (wave >= NN) return;
    int lane = threadIdx.x & 63;
    long base = (long)wave * 64;
    float acc = g[base + lane];
    int j0 = rowstart[wave], j1 = rowstart[wave + 1];
    for (int j = j0; j < j1; ++j) acc += g[(long)esrc[j] * 64 + lane];
    float v = acc * dinv[wave] + b[lane];
    out[base + lane] = v > 0.0f ? v : 0.0f;
}

// C = 64, final: split into mu / logstd halves of d_out, + bias
__global__ __launch_bounds__(256) void agg64_final_kernel(const int* __restrict__ rowstart,
                                                          const int* __restrict__ esrc,
                                                          const float* __restrict__ dinv,
                                                          const float* __restrict__ g,
                                                          const float* __restrict__ bmu,
                                                          const float* __restrict__ bls,
                                                          float* __restrict__ out) {
    int wave = blockIdx.x * (blockDim.x >> 6) + (threadIdx.x >> 6);
    if (wave >= NN) return;
    int lane = threadIdx.x & 63;
    long base = (long)wave * 64;
    float acc = g[base + lane];
    int j0 = rowstart[wave], j1 = rowstart[wave + 1];
    for (int j = j0; j < j1; ++j) acc += g[(long)esrc[j] * 64 + lane];
    float v = acc * dinv[wave];
    if (lane < 32)
        out[(long)wave * 32 + lane] = v + bmu[lane];
    else
        out[(long)NN * 32 + (long)wave * 32 + (lane - 32)] = v + bls[lane - 32];
}

// concat Wmu [64,32] | Wls [64,32] -> Wcat [64,64]
__global__ void wcat_kernel(const float* __restrict__ Wmu, const float* __restrict__ Wls,
                            float* __restrict__ Wcat) {
    int idx = blockIdx.x * blockDim.x + threadIdx.x;
    if (idx < 64 * 64) {
        int k = idx >> 6, c = idx & 63;
        Wcat[idx] = (c < 32) ? Wmu[k * 32 + c] : Wls[k * 32 + (c - 32)];
    }
}

// ---------------- GEMM: C[M,N] = A[M,K] @ B[K,N] (+bias+relu | *dinv[row]) ----------------
// TM = rows per thread (4 or 8). Tile: (TM*16) x 64, BK = 16.
// LDS fragments read as float4 (ds_read_b128): rows padded to BM+4 / 68 floats,
// both 16B multiples, so 16B alignment holds for m0%4==0 / n0%4==0.
template <int TM, bool RELU_BIAS, bool ROW_SCALE>
__global__ __launch_bounds__(256) void gemm_kernel(const float* __restrict__ A,
                                                   const float* __restrict__ B,
                                                   const float* __restrict__ bias,
                                                   const float* __restrict__ dinv,
                                                   float* __restrict__ C, int M, int N, int K) {
    const int BK = 16;
    const int BM = TM * 16;
    __shared__ float As[BK][BM + 4];  // [k][m]
    __shared__ float Bs[BK][68];      // [k][n]
    int tid = threadIdx.x;
    int bm0 = blockIdx.x * BM;
    int bn0 = blockIdx.y * 64;
    int m0 = (tid >> 4) * TM;
    int n0 = (tid & 15) * 4;
    float acc[TM][4] = {};
    for (int k0 = 0; k0 < K; k0 += BK) {
        for (int i = tid; i < BM * BK; i += 256) {
            int m = i >> 4, k = i & 15;
            int gm = bm0 + m, gk = k0 + k;
            As[k][m] = (gm < M && gk < K) ? A[(long)gm * K + gk] : 0.0f;
        }
        for (int i = tid; i < BK * 64; i += 256) {
            int k = i >> 6, n = i & 63;
            int gk = k0 + k, gn = bn0 + n;
            Bs[k][n] = (gk < K && gn < N) ? B[(long)gk * N + gn] : 0.0f;
        }
        __syncthreads();
        #pragma unroll
        for (int k = 0; k < BK; ++k) {
            float a[TM], b[4];
            *(float4*)&a[0] = *(const float4*)&As[k][m0];
            if (TM == 8) *(float4*)&a[4] = *(const float4*)&As[k][m0 + 4];
            *(float4*)&b[0] = *(const float4*)&Bs[k][n0];
            #pragma unroll
            for (int i = 0; i < TM; ++i)
                #pragma unroll
                for (int j = 0; j < 4; ++j) acc[i][j] = fmaf(a[i], b[j], acc[i][j]);
        }
        __syncthreads();
    }
    for (int i = 0; i < TM; ++i) {
        int gm = bm0 + m0 + i;
        if (gm >= M) break;
        float rs = ROW_SCALE ? dinv[gm] : 1.0f;
        #pragma unroll
        for (int j = 0; j < 4; ++j) {
            int gn = bn0 + n0 + j;
            if (gn >= N) continue;
            float v = acc[i][j];
            if (RELU_BIAS) {
                v += bias[gn];
                v = v > 0.0f ? v : 0.0f;
            }
            if (ROW_SCALE) v *= rs;
            C[(long)gm * N + gn] = v;
        }
    }
}

extern "C" void kernel_launch(void* const* d_in, const int* in_sizes, int n_in,
                              void* d_out, int out_size, void* d_ws, size_t ws_size,
                              hipStream_t stream) {
    const float* x   = (const float*)d_in[0];
    const int*   ei  = (const int*)d_in[1];
    const int*   src = ei;       // edge_index[0]
    const int*   dst = ei + NE;  // edge_index[1]
    const float* W1  = (const float*)d_in[2];
    const float* b1  = (const float*)d_in[3];
    const float* W2  = (const float*)d_in[4];
    const float* b2  = (const float*)d_in[5];
    const float* Wmu = (const float*)d_in[6];
    const float* bmu = (const float*)d_in[7];
    const float* Wls = (const float*)d_in[8];
    const float* bls = (const float*)d_in[9];
    float* out = (float*)d_out;

    // ---- workspace layout ----
    char* p = (char*)d_ws;
    float* dinv   = (float*)p; p += 50048 * 4;
    int* counts   = (int*)p;   p += 50048 * 4;  // counts+cursor zeroed together
    int* cursor   = (int*)p;   p += 50048 * 4;
    int* rowstart = (int*)p;   p += 50056 * 4;
    int* bsum     = (int*)p;   p += 256 * 4;
    int* esrc     = (int*)p;   p += 400000 * 4;
    float* bufA   = (float*)p; p += 5450240L * 4;  // xa (agg109 out), later h2
    float* bufB   = (float*)p; p += 5450240L * 4;  // g2, later g3
    float* h1     = (float*)p; p += 16000000L * 4;
    float* wcat   = (float*)p; p += 4096 * 4;

    const int TB = 256;
    const int NB_NODES = (NN + TB - 1) / TB;     // 196
    const int NB_AGG = (NN * 64 + TB - 1) / TB;  // 12500 (wave per node)

    // ---- CSR build ----
    zero_int_kernel<<<(100096 + TB - 1) / TB, TB, 0, stream>>>(counts, 100096);
    hist_kernel<<<1024, TB, 0, stream>>>(dst, counts);
    dinv_kernel<<<NB_NODES, TB, 0, stream>>>(counts, dinv);
    scan1_kernel<<<NB_NODES, TB, 0, stream>>>(counts, rowstart, bsum);
    scan2_kernel<<<1, 256, 0, stream>>>(bsum, NB_NODES);
    scan3_kernel<<<NB_NODES, TB, 0, stream>>>(rowstart, bsum);
    scatter_kernel<<<1024, TB, 0, stream>>>(src, dst, rowstart, cursor, esrc);

    // ---- layer 1: xa = agg(x) (dinv fused); h1 = relu(xa@W1 + b1) ----
    agg109_kernel<<<NB_AGG, TB, 0, stream>>>(rowstart, esrc, dinv, x, bufA);
    gemm_kernel<8, true, false><<<dim3(391, 5), 256, 0, stream>>>(bufA, W1, b1, nullptr, h1, NN, 320, 109);

    // ---- layer 2: g2 = (h1@W2)*dinv; h2 = relu(agg(g2) + b2) ----
    gemm_kernel<4, false, true><<<dim3(782, 1), 256, 0, stream>>>(h1, W2, nullptr, dinv, bufB, NN, 64, 320);
    agg64_relu_kernel<<<NB_AGG, TB, 0, stream>>>(rowstart, esrc, dinv, bufB, b2, bufA);

    // ---- layers 3+4: g3 = (h2@[Wmu|Wls])*dinv; out = agg(g3) + [bmu|bls] ----
    wcat_kernel<<<16, 256, 0, stream>>>(Wmu, Wls, wcat);
    gemm_kernel<4, false, true><<<dim3(782, 1), 256, 0, stream>>>(bufA, wcat, nullptr, dinv, bufB, NN, 64, 64);
    agg64_final_kernel<<<NB_AGG, TB, 0, stream>>>(rowstart, esrc, dinv, bufB, bmu, bls, out);
}

// Round 4
// 291.880 us; speedup vs baseline: 2.0978x; 1.3344x over previous
//
#include <hip/hip_runtime.h>

#define NN 50000
#define NE 400000

typedef __attribute__((ext_vector_type(8))) short short8v;
typedef __attribute__((ext_vector_type(4))) float f32x4;

__device__ __forceinline__ unsigned short f2bf_rtn(float x) {
    unsigned u = __float_as_uint(x);
    unsigned r = u + 0x7FFFu + ((u >> 16) & 1u);
    return (unsigned short)(r >> 16);
}
__device__ __forceinline__ float bf2f(unsigned short h) {
    return __uint_as_float(((unsigned)h) << 16);
}

// ---------------- degree / hist ----------------
__global__ void zero_int_kernel(int* __restrict__ p, int n) {
    int i = blockIdx.x * blockDim.x + threadIdx.x;
    if (i < n) p[i] = 0;
}

__global__ void hist_kernel(const int* __restrict__ dst, int* __restrict__ counts) {
    for (int e = blockIdx.x * blockDim.x + threadIdx.x; e < NE; e += gridDim.x * blockDim.x)
        atomicAdd(&counts[dst[e]], 1);
}

__global__ void dinv_kernel(const int* __restrict__ counts, float* __restrict__ dinv) {
    int i = blockIdx.x * blockDim.x + threadIdx.x;
    if (i < NN) dinv[i] = rsqrtf((float)(counts[i] + 1));  // +1 self loop
}

// ---------------- exclusive scan over counts -> rowstart ----------------
__global__ void scan1_kernel(const int* __restrict__ counts, int* __restrict__ rowstart,
                             int* __restrict__ bsum) {
    __shared__ int tmp[256];
    int tid = threadIdx.x;
    int i = blockIdx.x * 256 + tid;
    int v = (i < NN) ? counts[i] : 0;
    tmp[tid] = v;
    __syncthreads();
    for (int off = 1; off < 256; off <<= 1) {
        int t = 0;
        if (tid >= off) t = tmp[tid - off];
        __syncthreads();
        if (tid >= off) tmp[tid] += t;
        __syncthreads();
    }
    if (i < NN) rowstart[i] = tmp[tid] - v;  // exclusive
    if (tid == 255) bsum[blockIdx.x] = tmp[255];
}

__global__ void scan2_kernel(int* __restrict__ bsum, int nb) {
    __shared__ int tmp[256];
    int tid = threadIdx.x;
    int v = (tid < nb) ? bsum[tid] : 0;
    tmp[tid] = v;
    __syncthreads();
    for (int off = 1; off < 256; off <<= 1) {
        int t = 0;
        if (tid >= off) t = tmp[tid - off];
        __syncthreads();
        if (tid >= off) tmp[tid] += t;
        __syncthreads();
    }
    if (tid < nb) bsum[tid] = tmp[tid] - v;  // exclusive
}

__global__ void scan3_kernel(int* __restrict__ rowstart, const int* __restrict__ bsum) {
    int i = blockIdx.x * 256 + threadIdx.x;
    if (i < NN) rowstart[i] += bsum[blockIdx.x];
    if (i == 0) rowstart[NN] = NE;
}

__global__ void scatter_kernel(const int* __restrict__ src, const int* __restrict__ dst,
                               const int* __restrict__ rowstart, int* __restrict__ cursor,
                               int* __restrict__ esrc) {
    for (int e = blockIdx.x * blockDim.x + threadIdx.x; e < NE; e += gridDim.x * blockDim.x) {
        int d = dst[e];
        int pos = rowstart[d] + atomicAdd(&cursor[d], 1);
        esrc[pos] = src[e];
    }
}

// ---------------- CSR aggregation, layer 1 -> bf16 hi/lo, K padded to 128 ----------------
__global__ __launch_bounds__(256) void agg109_bf16_kernel(const int* __restrict__ rowstart,
                                                          const int* __restrict__ esrc,
                                                          const float* __restrict__ dinv,
                                                          const float* __restrict__ x,
                                                          unsigned short* __restrict__ xa_hi,
                                                          unsigned short* __restrict__ xa_lo) {
    int wave = blockIdx.x * (blockDim.x >> 6) + (threadIdx.x >> 6);
    if (wave >= NN) return;
    int lane = threadIdx.x & 63;
    long base = (long)wave * 109;
    float wd = dinv[wave];
    float acc0 = x[base + lane] * wd;
    float acc1 = (lane < 45) ? x[base + 64 + lane] * wd : 0.0f;
    int j0 = rowstart[wave], j1 = rowstart[wave + 1];
    for (int j = j0; j < j1; ++j) {
        int s = esrc[j];
        long sb = (long)s * 109;
        float w = dinv[s];
        acc0 += x[sb + lane] * w;
        if (lane < 45) acc1 += x[sb + 64 + lane] * w;
    }
    acc0 *= wd;
    float v1 = (lane < 45) ? acc1 * wd : 0.0f;  // cols 109..127 zero-padded
    long ob = (long)wave * 128;
    unsigned short h0 = f2bf_rtn(acc0);
    xa_hi[ob + lane] = h0;
    xa_lo[ob + lane] = f2bf_rtn(acc0 - bf2f(h0));
    unsigned short h1 = f2bf_rtn(v1);
    xa_hi[ob + 64 + lane] = h1;
    xa_lo[ob + 64 + lane] = (lane < 45) ? f2bf_rtn(v1 - bf2f(h1)) : (unsigned short)0;
}

// C = 64, epilogue: relu(v * dinv + b) -> bf16 hi/lo
__global__ __launch_bounds__(256) void agg64_relu_bf16_kernel(const int* __restrict__ rowstart,
                                                              const int* __restrict__ esrc,
                                                              const float* __restrict__ dinv,
                                                              const float* __restrict__ g,
                                                              const float* __restrict__ b,
                                                              unsigned short* __restrict__ hhi,
                                                              unsigned short* __restrict__ hlo) {
    int wave = blockIdx.x * (blockDim.x >> 6) + (threadIdx.x >> 6);
    if (wave >= NN) return;
    int lane = threadIdx.x & 63;
    long base = (long)wave * 64;
    float acc = g[base + lane];
    int j0 = rowstart[wave], j1 = rowstart[wave + 1];
    for (int j = j0; j < j1; ++j) acc += g[(long)esrc[j] * 64 + lane];
    float v = acc * dinv[wave] + b[lane];
    v = v > 0.0f ? v : 0.0f;
    unsigned short hb = f2bf_rtn(v);
    hhi[base + lane] = hb;
    hlo[base + lane] = f2bf_rtn(v - bf2f(hb));
}

// C = 64, final: split into mu / logstd halves of d_out, + bias
__global__ __launch_bounds__(256) void agg64_final_kernel(const int* __restrict__ rowstart,
                                                          const int* __restrict__ esrc,
                                                          const float* __restrict__ dinv,
                                                          const float* __restrict__ g,
                                                          const float* __restrict__ bmu,
                                                          const float* __restrict__ bls,
                                                          float* __restrict__ out) {
    int wave = blockIdx.x * (blockDim.x >> 6) + (threadIdx.x >> 6);
    if (wave >= NN) return;
    int lane = threadIdx.x & 63;
    long base = (long)wave * 64;
    float acc = g[base + lane];
    int j0 = rowstart[wave], j1 = rowstart[wave + 1];
    for (int j = j0; j < j1; ++j) acc += g[(long)esrc[j] * 64 + lane];
    float v = acc * dinv[wave];
    if (lane < 32)
        out[(long)wave * 32 + lane] = v + bmu[lane];
    else
        out[(long)NN * 32 + (long)wave * 32 + (lane - 32)] = v + bls[lane - 32];
}

// ---------------- weight conversion: src[Kreal][N] fp32 -> dst[N][KP] bf16 hi/lo ----------------
__global__ void convT_kernel(const float* __restrict__ src, int Kreal, int KP, int N,
                             unsigned short* __restrict__ dhi, unsigned short* __restrict__ dlo) {
    int idx = blockIdx.x * blockDim.x + threadIdx.x;
    if (idx >= N * KP) return;
    int n = idx / KP, k = idx - n * KP;
    float v = (k < Kreal) ? src[(long)k * N + n] : 0.0f;
    unsigned short hb = f2bf_rtn(v);
    dhi[idx] = hb;
    dlo[idx] = f2bf_rtn(v - bf2f(hb));
}

// [Wmu | Wls] -> wcatT[64][64] bf16 hi/lo
__global__ void convWcat_kernel(const float* __restrict__ Wmu, const float* __restrict__ Wls,
                                unsigned short* __restrict__ dhi, unsigned short* __restrict__ dlo) {
    int idx = blockIdx.x * blockDim.x + threadIdx.x;
    if (idx >= 4096) return;
    int n = idx >> 6, k = idx & 63;
    float v = (n < 32) ? Wmu[k * 32 + n] : Wls[k * 32 + (n - 32)];
    unsigned short hb = f2bf_rtn(v);
    dhi[idx] = hb;
    dlo[idx] = f2bf_rtn(v - bf2f(hb));
}

// ---------------- split-bf16 MFMA GEMM ----------------
// C[M,N] = A[M,K] @ B^T[N,K]  (A,B as hi/lo bf16 pairs; K multiple of 64)
// block: 4 waves, tile 128(M) x 64(N); wave: 32 rows x 64 cols; BK=64.
// MODE 0: v = relu(acc + bias[col]) -> Chi/Clo bf16 pair.  MODE 1: v = acc*dinv[row] -> Cf fp32.
#define LDT 72  // LDS row stride (bf16 elems); 144 B -> <=2-way bank aliasing (free)

template <int MODE>
__global__ __launch_bounds__(256) void mfma_gemm_kernel(
    const unsigned short* __restrict__ Ahi, const unsigned short* __restrict__ Alo,
    const unsigned short* __restrict__ Bhi, const unsigned short* __restrict__ Blo,
    const float* __restrict__ bias, const float* __restrict__ dinv,
    unsigned short* __restrict__ Chi, unsigned short* __restrict__ Clo,
    float* __restrict__ Cf, int M, int N, int K) {
    __shared__ unsigned short As[2 * 128 * LDT];  // hi at 0, lo at 128*LDT
    __shared__ unsigned short Bs[2 * 64 * LDT];
    int tid = threadIdx.x;
    int wid = tid >> 6, lane = tid & 63;
    int l15 = lane & 15, l4 = lane >> 4;
    int bm0 = blockIdx.x * 128;
    int bn0 = blockIdx.y * 64;
    f32x4 acc[2][4] = {};

    for (int kc = 0; kc < K; kc += 64) {
        // stage A tile (128x64 hi + lo) as 16B pieces
        #pragma unroll
        for (int r = 0; r < 4; ++r) {
            int idx = tid + 256 * r;
            int row = idx >> 3, slot = idx & 7;
            int grow = bm0 + row;
            if (grow >= M) grow = M - 1;  // clamp; epilogue guards stores
            long go = (long)grow * K + kc + slot * 8;
            *(uint4*)&As[row * LDT + slot * 8] = *(const uint4*)&Ahi[go];
            *(uint4*)&As[128 * LDT + row * LDT + slot * 8] = *(const uint4*)&Alo[go];
        }
        // stage B tile (64x64 hi + lo)
        #pragma unroll
        for (int r = 0; r < 2; ++r) {
            int idx = tid + 256 * r;
            int row = idx >> 3, slot = idx & 7;
            long go = (long)(bn0 + row) * K + kc + slot * 8;
            *(uint4*)&Bs[row * LDT + slot * 8] = *(const uint4*)&Bhi[go];
            *(uint4*)&Bs[64 * LDT + row * LDT + slot * 8] = *(const uint4*)&Blo[go];
        }
        __syncthreads();
        #pragma unroll
        for (int ks = 0; ks < 2; ++ks) {
            int koff = ks * 32 + l4 * 8;
            short8v ah[2], al[2], bh[4], bl[4];
            #pragma unroll
            for (int m = 0; m < 2; ++m) {
                int rb = (wid * 32 + m * 16 + l15) * LDT + koff;
                ah[m] = *(const short8v*)&As[rb];
                al[m] = *(const short8v*)&As[128 * LDT + rb];
            }
            #pragma unroll
            for (int n = 0; n < 4; ++n) {
                int rb = (n * 16 + l15) * LDT + koff;
                bh[n] = *(const short8v*)&Bs[rb];
                bl[n] = *(const short8v*)&Bs[64 * LDT + rb];
            }
            #pragma unroll
            for (int m = 0; m < 2; ++m)
                #pragma unroll
                for (int n = 0; n < 4; ++n) {
                    acc[m][n] = __builtin_amdgcn_mfma_f32_16x16x32_bf16(ah[m], bh[n], acc[m][n], 0, 0, 0);
                    acc[m][n] = __builtin_amdgcn_mfma_f32_16x16x32_bf16(al[m], bh[n], acc[m][n], 0, 0, 0);
                    acc[m][n] = __builtin_amdgcn_mfma_f32_16x16x32_bf16(ah[m], bl[n], acc[m][n], 0, 0, 0);
                }
        }
        __syncthreads();
    }
    // epilogue: C/D frag mapping col=lane&15, row=(lane>>4)*4+reg
    #pragma unroll
    for (int m = 0; m < 2; ++m) {
        int rbase = bm0 + wid * 32 + m * 16 + l4 * 4;
        #pragma unroll
        for (int q = 0; q < 4; ++q) {
            int grow = rbase + q;
            if (grow >= M) continue;
            float rs = (MODE == 1) ? dinv[grow] : 0.0f;
            #pragma unroll
            for (int n = 0; n < 4; ++n) {
                int gcol = bn0 + n * 16 + l15;
                float v = acc[m][n][q];
                if (MODE == 0) {
                    v += bias[gcol];
                    v = v > 0.0f ? v : 0.0f;
                    unsigned short hb = f2bf_rtn(v);
                    long o = (long)grow * N + gcol;
                    Chi[o] = hb;
                    Clo[o] = f2bf_rtn(v - bf2f(hb));
                } else {
                    Cf[(long)grow * N + gcol] = v * rs;
                }
            }
        }
    }
}

extern "C" void kernel_launch(void* const* d_in, const int* in_sizes, int n_in,
                              void* d_out, int out_size, void* d_ws, size_t ws_size,
                              hipStream_t stream) {
    const float* x   = (const float*)d_in[0];
    const int*   ei  = (const int*)d_in[1];
    const int*   src = ei;       // edge_index[0]
    const int*   dst = ei + NE;  // edge_index[1]
    const float* W1  = (const float*)d_in[2];
    const float* b1  = (const float*)d_in[3];
    const float* W2  = (const float*)d_in[4];
    const float* b2  = (const float*)d_in[5];
    const float* Wmu = (const float*)d_in[6];
    const float* bmu = (const float*)d_in[7];
    const float* Wls = (const float*)d_in[8];
    const float* bls = (const float*)d_in[9];
    float* out = (float*)d_out;

    // ---- workspace layout (~105 MB) ----
    char* p = (char*)d_ws;
    float* dinv   = (float*)p; p += 50048 * 4;
    int* counts   = (int*)p;   p += 50048 * 4;
    int* cursor   = (int*)p;   p += 50048 * 4;
    int* rowstart = (int*)p;   p += 50056 * 4;
    int* bsum     = (int*)p;   p += 256 * 4;
    int* esrc     = (int*)p;   p += 400000 * 4;
    unsigned short* xa_hi = (unsigned short*)p; p += 50000L * 128 * 2;  // later h2_hi
    unsigned short* xa_lo = (unsigned short*)p; p += 50000L * 128 * 2;  // later h2_lo
    unsigned short* h1_hi = (unsigned short*)p; p += 50000L * 320 * 2;
    unsigned short* h1_lo = (unsigned short*)p; p += 50000L * 320 * 2;
    float* g2             = (float*)p;          p += 50000L * 64 * 4;   // later g3
    unsigned short* w1t_hi = (unsigned short*)p; p += 320 * 128 * 2;
    unsigned short* w1t_lo = (unsigned short*)p; p += 320 * 128 * 2;
    unsigned short* w2t_hi = (unsigned short*)p; p += 64 * 320 * 2;
    unsigned short* w2t_lo = (unsigned short*)p; p += 64 * 320 * 2;
    unsigned short* wct_hi = (unsigned short*)p; p += 64 * 64 * 2;
    unsigned short* wct_lo = (unsigned short*)p; p += 64 * 64 * 2;
    unsigned short* h2_hi = xa_hi;  // xa dead after GEMM1
    unsigned short* h2_lo = xa_lo;

    const int TB = 256;
    const int NB_NODES = (NN + TB - 1) / TB;     // 196
    const int NB_AGG = (NN * 64 + TB - 1) / TB;  // 12500 (wave per node)

    // ---- CSR build ----
    zero_int_kernel<<<(100096 + TB - 1) / TB, TB, 0, stream>>>(counts, 100096);
    hist_kernel<<<1024, TB, 0, stream>>>(dst, counts);
    dinv_kernel<<<NB_NODES, TB, 0, stream>>>(counts, dinv);
    scan1_kernel<<<NB_NODES, TB, 0, stream>>>(counts, rowstart, bsum);
    scan2_kernel<<<1, 256, 0, stream>>>(bsum, NB_NODES);
    scan3_kernel<<<NB_NODES, TB, 0, stream>>>(rowstart, bsum);
    scatter_kernel<<<1024, TB, 0, stream>>>(src, dst, rowstart, cursor, esrc);

    // ---- weight conversions ----
    convT_kernel<<<160, 256, 0, stream>>>(W1, 109, 128, 320, w1t_hi, w1t_lo);
    convT_kernel<<<80, 256, 0, stream>>>(W2, 320, 320, 64, w2t_hi, w2t_lo);
    convWcat_kernel<<<16, 256, 0, stream>>>(Wmu, Wls, wct_hi, wct_lo);

    // ---- layer 1: xa = agg(x) -> bf16 pair; h1 = relu(xa@W1 + b1) -> bf16 pair ----
    agg109_bf16_kernel<<<NB_AGG, TB, 0, stream>>>(rowstart, esrc, dinv, x, xa_hi, xa_lo);
    mfma_gemm_kernel<0><<<dim3(391, 5), 256, 0, stream>>>(xa_hi, xa_lo, w1t_hi, w1t_lo, b1,
                                                          nullptr, h1_hi, h1_lo, nullptr,
                                                          NN, 320, 128);

    // ---- layer 2: g2 = (h1@W2)*dinv; h2 = relu(agg(g2) + b2) -> bf16 pair ----
    mfma_gemm_kernel<1><<<dim3(391, 1), 256, 0, stream>>>(h1_hi, h1_lo, w2t_hi, w2t_lo, nullptr,
                                                          dinv, nullptr, nullptr, g2,
                                                          NN, 64, 320);
    agg64_relu_bf16_kernel<<<NB_AGG, TB, 0, stream>>>(rowstart, esrc, dinv, g2, b2, h2_hi, h2_lo);

    // ---- layers 3+4: g3 = (h2@[Wmu|Wls])*dinv; out = agg(g3) + [bmu|bls] ----
    mfma_gemm_kernel<1><<<dim3(391, 1), 256, 0, stream>>>(h2_hi, h2_lo, wct_hi, wct_lo, nullptr,
                                                          dinv, nullptr, nullptr, g2,
                                                          NN, 64, 64);
    agg64_final_kernel<<<NB_AGG, TB, 0, stream>>>(rowstart, esrc, dinv, g2, bmu, bls, out);
}

// Round 5
// 239.473 us; speedup vs baseline: 2.5568x; 1.2188x over previous
//
#include <hip/hip_runtime.h>

#define NN 50000
#define NE 400000

typedef __attribute__((ext_vector_type(8))) short short8v;
typedef __attribute__((ext_vector_type(4))) float f32x4;

__device__ __forceinline__ unsigned short f2bf_rtn(float x) {
    unsigned u = __float_as_uint(x);
    unsigned r = u + 0x7FFFu + ((u >> 16) & 1u);
    return (unsigned short)(r >> 16);
}
__device__ __forceinline__ float bf2f(unsigned short h) {
    return __uint_as_float(((unsigned)h) << 16);
}

// ---------------- degree / hist ----------------
__global__ void zero_int_kernel(int* __restrict__ p, int n) {
    int i = blockIdx.x * blockDim.x + threadIdx.x;
    if (i < n) p[i] = 0;
}

__global__ void hist_kernel(const int* __restrict__ dst, int* __restrict__ counts) {
    for (int e = blockIdx.x * blockDim.x + threadIdx.x; e < NE; e += gridDim.x * blockDim.x)
        atomicAdd(&counts[dst[e]], 1);
}

__global__ void dinv_kernel(const int* __restrict__ counts, float* __restrict__ dinv) {
    int i = blockIdx.x * blockDim.x + threadIdx.x;
    if (i < NN) dinv[i] = rsqrtf((float)(counts[i] + 1));  // +1 self loop
}

// ---------------- exclusive scan over counts -> rowstart ----------------
__global__ void scan1_kernel(const int* __restrict__ counts, int* __restrict__ rowstart,
                             int* __restrict__ bsum) {
    __shared__ int tmp[256];
    int tid = threadIdx.x;
    int i = blockIdx.x * 256 + tid;
    int v = (i < NN) ? counts[i] : 0;
    tmp[tid] = v;
    __syncthreads();
    for (int off = 1; off < 256; off <<= 1) {
        int t = 0;
        if (tid >= off) t = tmp[tid - off];
        __syncthreads();
        if (tid >= off) tmp[tid] += t;
        __syncthreads();
    }
    if (i < NN) rowstart[i] = tmp[tid] - v;  // exclusive
    if (tid == 255) bsum[blockIdx.x] = tmp[255];
}

__global__ void scan2_kernel(int* __restrict__ bsum, int nb) {
    __shared__ int tmp[256];
    int tid = threadIdx.x;
    int v = (tid < nb) ? bsum[tid] : 0;
    tmp[tid] = v;
    __syncthreads();
    for (int off = 1; off < 256; off <<= 1) {
        int t = 0;
        if (tid >= off) t = tmp[tid - off];
        __syncthreads();
        if (tid >= off) tmp[tid] += t;
        __syncthreads();
    }
    if (tid < nb) bsum[tid] = tmp[tid] - v;  // exclusive
}

__global__ void scan3_kernel(int* __restrict__ rowstart, const int* __restrict__ bsum) {
    int i = blockIdx.x * 256 + threadIdx.x;
    if (i < NN) rowstart[i] += bsum[blockIdx.x];
    if (i == 0) rowstart[NN] = NE;
}

__global__ void scatter_kernel(const int* __restrict__ src, const int* __restrict__ dst,
                               const int* __restrict__ rowstart, int* __restrict__ cursor,
                               int* __restrict__ esrc) {
    for (int e = blockIdx.x * blockDim.x + threadIdx.x; e < NE; e += gridDim.x * blockDim.x) {
        int d = dst[e];
        int pos = rowstart[d] + atomicAdd(&cursor[d], 1);
        esrc[pos] = src[e];
    }
}

// ---------------- CSR aggregation, layer 1 -> bf16 hi/lo, K padded to 128 ----------------
// unroll x4: 4 independent row gathers in flight per wave
__global__ __launch_bounds__(256) void agg109_bf16_kernel(const int* __restrict__ rowstart,
                                                          const int* __restrict__ esrc,
                                                          const float* __restrict__ dinv,
                                                          const float* __restrict__ x,
                                                          unsigned short* __restrict__ xa_hi,
                                                          unsigned short* __restrict__ xa_lo) {
    int wave = blockIdx.x * (blockDim.x >> 6) + (threadIdx.x >> 6);
    if (wave >= NN) return;
    int lane = threadIdx.x & 63;
    bool lo45 = lane < 45;
    long base = (long)wave * 109;
    float wd = dinv[wave];
    float acc0 = x[base + lane] * wd;
    float acc1 = lo45 ? x[base + 64 + lane] * wd : 0.0f;
    int j0 = rowstart[wave], j1 = rowstart[wave + 1];
    int j = j0;
    for (; j + 4 <= j1; j += 4) {
        int s0 = esrc[j], s1 = esrc[j + 1], s2 = esrc[j + 2], s3 = esrc[j + 3];
        float w0 = dinv[s0], w1 = dinv[s1], w2 = dinv[s2], w3 = dinv[s3];
        long b0 = (long)s0 * 109, b1 = (long)s1 * 109, b2 = (long)s2 * 109, b3 = (long)s3 * 109;
        float p0 = x[b0 + lane], p1 = x[b1 + lane], p2 = x[b2 + lane], p3 = x[b3 + lane];
        float q0 = 0, q1 = 0, q2 = 0, q3 = 0;
        if (lo45) {
            q0 = x[b0 + 64 + lane]; q1 = x[b1 + 64 + lane];
            q2 = x[b2 + 64 + lane]; q3 = x[b3 + 64 + lane];
        }
        acc0 = fmaf(p0, w0, acc0); acc0 = fmaf(p1, w1, acc0);
        acc0 = fmaf(p2, w2, acc0); acc0 = fmaf(p3, w3, acc0);
        acc1 = fmaf(q0, w0, acc1); acc1 = fmaf(q1, w1, acc1);
        acc1 = fmaf(q2, w2, acc1); acc1 = fmaf(q3, w3, acc1);
    }
    for (; j < j1; ++j) {
        int s = esrc[j];
        long sb = (long)s * 109;
        float w = dinv[s];
        acc0 = fmaf(x[sb + lane], w, acc0);
        if (lo45) acc1 = fmaf(x[sb + 64 + lane], w, acc1);
    }
    acc0 *= wd;
    float v1 = lo45 ? acc1 * wd : 0.0f;  // cols 109..127 zero-padded
    long ob = (long)wave * 128;
    unsigned short h0 = f2bf_rtn(acc0);
    xa_hi[ob + lane] = h0;
    xa_lo[ob + lane] = f2bf_rtn(acc0 - bf2f(h0));
    unsigned short h1 = f2bf_rtn(v1);
    xa_hi[ob + 64 + lane] = h1;
    xa_lo[ob + 64 + lane] = lo45 ? f2bf_rtn(v1 - bf2f(h1)) : (unsigned short)0;
}

// C = 64, epilogue: relu(v * dinv + b) -> bf16 hi/lo; unroll x4
__global__ __launch_bounds__(256) void agg64_relu_bf16_kernel(const int* __restrict__ rowstart,
                                                              const int* __restrict__ esrc,
                                                              const float* __restrict__ dinv,
                                                              const float* __restrict__ g,
                                                              const float* __restrict__ b,
                                                              unsigned short* __restrict__ hhi,
                                                              unsigned short* __restrict__ hlo) {
    int wave = blockIdx.x * (blockDim.x >> 6) + (threadIdx.x >> 6);
    if (wave >= NN) return;
    int lane = threadIdx.x & 63;
    long base = (long)wave * 64;
    float acc = g[base + lane];
    int j0 = rowstart[wave], j1 = rowstart[wave + 1];
    int j = j0;
    for (; j + 4 <= j1; j += 4) {
        int s0 = esrc[j], s1 = esrc[j + 1], s2 = esrc[j + 2], s3 = esrc[j + 3];
        float p0 = g[(long)s0 * 64 + lane], p1 = g[(long)s1 * 64 + lane];
        float p2 = g[(long)s2 * 64 + lane], p3 = g[(long)s3 * 64 + lane];
        acc += p0 + p1 + p2 + p3;
    }
    for (; j < j1; ++j) acc += g[(long)esrc[j] * 64 + lane];
    float v = acc * dinv[wave] + b[lane];
    v = v > 0.0f ? v : 0.0f;
    unsigned short hb = f2bf_rtn(v);
    hhi[base + lane] = hb;
    hlo[base + lane] = f2bf_rtn(v - bf2f(hb));
}

// C = 64, final: split into mu / logstd halves of d_out, + bias; unroll x4
__global__ __launch_bounds__(256) void agg64_final_kernel(const int* __restrict__ rowstart,
                                                          const int* __restrict__ esrc,
                                                          const float* __restrict__ dinv,
                                                          const float* __restrict__ g,
                                                          const float* __restrict__ bmu,
                                                          const float* __restrict__ bls,
                                                          float* __restrict__ out) {
    int wave = blockIdx.x * (blockDim.x >> 6) + (threadIdx.x >> 6);
    if (wave >= NN) return;
    int lane = threadIdx.x & 63;
    long base = (long)wave * 64;
    float acc = g[base + lane];
    int j0 = rowstart[wave], j1 = rowstart[wave + 1];
    int j = j0;
    for (; j + 4 <= j1; j += 4) {
        int s0 = esrc[j], s1 = esrc[j + 1], s2 = esrc[j + 2], s3 = esrc[j + 3];
        float p0 = g[(long)s0 * 64 + lane], p1 = g[(long)s1 * 64 + lane];
        float p2 = g[(long)s2 * 64 + lane], p3 = g[(long)s3 * 64 + lane];
        acc += p0 + p1 + p2 + p3;
    }
    for (; j < j1; ++j) acc += g[(long)esrc[j] * 64 + lane];
    float v = acc * dinv[wave];
    if (lane < 32)
        out[(long)wave * 32 + lane] = v + bmu[lane];
    else
        out[(long)NN * 32 + (long)wave * 32 + (lane - 32)] = v + bls[lane - 32];
}

// ---------------- weight conversion: src[Kreal][N] fp32 -> dst[N][KP] bf16 hi/lo ----------------
__global__ void convT_kernel(const float* __restrict__ src, int Kreal, int KP, int N,
                             unsigned short* __restrict__ dhi, unsigned short* __restrict__ dlo) {
    int idx = blockIdx.x * blockDim.x + threadIdx.x;
    if (idx >= N * KP) return;
    int n = idx / KP, k = idx - n * KP;
    float v = (k < Kreal) ? src[(long)k * N + n] : 0.0f;
    unsigned short hb = f2bf_rtn(v);
    dhi[idx] = hb;
    dlo[idx] = f2bf_rtn(v - bf2f(hb));
}

// [Wmu | Wls] -> wcatT[64][64] bf16 hi/lo
__global__ void convWcat_kernel(const float* __restrict__ Wmu, const float* __restrict__ Wls,
                                unsigned short* __restrict__ dhi, unsigned short* __restrict__ dlo) {
    int idx = blockIdx.x * blockDim.x + threadIdx.x;
    if (idx >= 4096) return;
    int n = idx >> 6, k = idx & 63;
    float v = (n < 32) ? Wmu[k * 32 + n] : Wls[k * 32 + (n - 32)];
    unsigned short hb = f2bf_rtn(v);
    dhi[idx] = hb;
    dlo[idx] = f2bf_rtn(v - bf2f(hb));
}

// ---------------- split-bf16 MFMA GEMM ----------------
// C[M,N] = A[M,K] @ B^T[N,K]  (A,B as hi/lo bf16 pairs; K multiple of 64)
// block: 4 waves, tile 128(M) x 64(N); wave: 32 rows x 64 cols; BK=64.
// MODE 0: v = relu(acc + bias[col]) -> Chi/Clo bf16 pair.  MODE 1: v = acc*dinv[row] -> Cf fp32.
#define LDT 72  // LDS row stride (bf16 elems); 144 B -> <=2-way bank aliasing (free)

template <int MODE>
__global__ __launch_bounds__(256) void mfma_gemm_kernel(
    const unsigned short* __restrict__ Ahi, const unsigned short* __restrict__ Alo,
    const unsigned short* __restrict__ Bhi, const unsigned short* __restrict__ Blo,
    const float* __restrict__ bias, const float* __restrict__ dinv,
    unsigned short* __restrict__ Chi, unsigned short* __restrict__ Clo,
    float* __restrict__ Cf, int M, int N, int K) {
    __shared__ unsigned short As[2 * 128 * LDT];  // hi at 0, lo at 128*LDT
    __shared__ unsigned short Bs[2 * 64 * LDT];
    int tid = threadIdx.x;
    int wid = tid >> 6, lane = tid & 63;
    int l15 = lane & 15, l4 = lane >> 4;
    int bm0 = blockIdx.x * 128;
    int bn0 = blockIdx.y * 64;
    f32x4 acc[2][4] = {};

    for (int kc = 0; kc < K; kc += 64) {
        // stage A tile (128x64 hi + lo) as 16B pieces
        #pragma unroll
        for (int r = 0; r < 4; ++r) {
            int idx = tid + 256 * r;
            int row = idx >> 3, slot = idx & 7;
            int grow = bm0 + row;
            if (grow >= M) grow = M - 1;  // clamp; epilogue guards stores
            long go = (long)grow * K + kc + slot * 8;
            *(uint4*)&As[row * LDT + slot * 8] = *(const uint4*)&Ahi[go];
            *(uint4*)&As[128 * LDT + row * LDT + slot * 8] = *(const uint4*)&Alo[go];
        }
        // stage B tile (64x64 hi + lo)
        #pragma unroll
        for (int r = 0; r < 2; ++r) {
            int idx = tid + 256 * r;
            int row = idx >> 3, slot = idx & 7;
            long go = (long)(bn0 + row) * K + kc + slot * 8;
            *(uint4*)&Bs[row * LDT + slot * 8] = *(const uint4*)&Bhi[go];
            *(uint4*)&Bs[64 * LDT + row * LDT + slot * 8] = *(const uint4*)&Blo[go];
        }
        __syncthreads();
        #pragma unroll
        for (int ks = 0; ks < 2; ++ks) {
            int koff = ks * 32 + l4 * 8;
            short8v ah[2], al[2], bh[4], bl[4];
            #pragma unroll
            for (int m = 0; m < 2; ++m) {
                int rb = (wid * 32 + m * 16 + l15) * LDT + koff;
                ah[m] = *(const short8v*)&As[rb];
                al[m] = *(const short8v*)&As[128 * LDT + rb];
            }
            #pragma unroll
            for (int n = 0; n < 4; ++n) {
                int rb = (n * 16 + l15) * LDT + koff;
                bh[n] = *(const short8v*)&Bs[rb];
                bl[n] = *(const short8v*)&Bs[64 * LDT + rb];
            }
            #pragma unroll
            for (int m = 0; m < 2; ++m)
                #pragma unroll
                for (int n = 0; n < 4; ++n) {
                    acc[m][n] = __builtin_amdgcn_mfma_f32_16x16x32_bf16(ah[m], bh[n], acc[m][n], 0, 0, 0);
                    acc[m][n] = __builtin_amdgcn_mfma_f32_16x16x32_bf16(al[m], bh[n], acc[m][n], 0, 0, 0);
                    acc[m][n] = __builtin_amdgcn_mfma_f32_16x16x32_bf16(ah[m], bl[n], acc[m][n], 0, 0, 0);
                }
        }
        __syncthreads();
    }
    // epilogue: C/D frag mapping col=lane&15, row=(lane>>4)*4+reg
    #pragma unroll
    for (int m = 0; m < 2; ++m) {
        int rbase = bm0 + wid * 32 + m * 16 + l4 * 4;
        #pragma unroll
        for (int q = 0; q < 4; ++q) {
            int grow = rbase + q;
            if (grow >= M) continue;
            float rs = (MODE == 1) ? dinv[grow] : 0.0f;
            #pragma unroll
            for (int n = 0; n < 4; ++n) {
                int gcol = bn0 + n * 16 + l15;
                float v = acc[m][n][q];
                if (MODE == 0) {
                    v += bias[gcol];
                    v = v > 0.0f ? v : 0.0f;
                    unsigned short hb = f2bf_rtn(v);
                    long o = (long)grow * N + gcol;
                    Chi[o] = hb;
                    Clo[o] = f2bf_rtn(v - bf2f(hb));
                } else {
                    Cf[(long)grow * N + gcol] = v * rs;
                }
            }
        }
    }
}

extern "C" void kernel_launch(void* const* d_in, const int* in_sizes, int n_in,
                              void* d_out, int out_size, void* d_ws, size_t ws_size,
                              hipStream_t stream) {
    const float* x   = (const float*)d_in[0];
    const int*   ei  = (const int*)d_in[1];
    const int*   src = ei;       // edge_index[0]
    const int*   dst = ei + NE;  // edge_index[1]
    const float* W1  = (const float*)d_in[2];
    const float* b1  = (const float*)d_in[3];
    const float* W2  = (const float*)d_in[4];
    const float* b2  = (const float*)d_in[5];
    const float* Wmu = (const float*)d_in[6];
    const float* bmu = (const float*)d_in[7];
    const float* Wls = (const float*)d_in[8];
    const float* bls = (const float*)d_in[9];
    float* out = (float*)d_out;

    // ---- workspace layout (~105 MB) ----
    char* p = (char*)d_ws;
    float* dinv   = (float*)p; p += 50048 * 4;
    int* counts   = (int*)p;   p += 50048 * 4;
    int* cursor   = (int*)p;   p += 50048 * 4;
    int* rowstart = (int*)p;   p += 50056 * 4;
    int* bsum     = (int*)p;   p += 256 * 4;
    int* esrc     = (int*)p;   p += 400000 * 4;
    unsigned short* xa_hi = (unsigned short*)p; p += 50000L * 128 * 2;  // later h2_hi
    unsigned short* xa_lo = (unsigned short*)p; p += 50000L * 128 * 2;  // later h2_lo
    unsigned short* h1_hi = (unsigned short*)p; p += 50000L * 320 * 2;
    unsigned short* h1_lo = (unsigned short*)p; p += 50000L * 320 * 2;
    float* g2             = (float*)p;          p += 50000L * 64 * 4;   // later g3
    unsigned short* w1t_hi = (unsigned short*)p; p += 320 * 128 * 2;
    unsigned short* w1t_lo = (unsigned short*)p; p += 320 * 128 * 2;
    unsigned short* w2t_hi = (unsigned short*)p; p += 64 * 320 * 2;
    unsigned short* w2t_lo = (unsigned short*)p; p += 64 * 320 * 2;
    unsigned short* wct_hi = (unsigned short*)p; p += 64 * 64 * 2;
    unsigned short* wct_lo = (unsigned short*)p; p += 64 * 64 * 2;
    unsigned short* h2_hi = xa_hi;  // xa dead after GEMM1
    unsigned short* h2_lo = xa_lo;

    const int TB = 256;
    const int NB_NODES = (NN + TB - 1) / TB;     // 196
    const int NB_AGG = (NN * 64 + TB - 1) / TB;  // 12500 (wave per node)

    // ---- CSR build ----
    zero_int_kernel<<<(100096 + TB - 1) / TB, TB, 0, stream>>>(counts, 100096);
    hist_kernel<<<1024, TB, 0, stream>>>(dst, counts);
    dinv_kernel<<<NB_NODES, TB, 0, stream>>>(counts, dinv);
    scan1_kernel<<<NB_NODES, TB, 0, stream>>>(counts, rowstart, bsum);
    scan2_kernel<<<1, 256, 0, stream>>>(bsum, NB_NODES);
    scan3_kernel<<<NB_NODES, TB, 0, stream>>>(rowstart, bsum);
    scatter_kernel<<<1024, TB, 0, stream>>>(src, dst, rowstart, cursor, esrc);

    // ---- weight conversions ----
    convT_kernel<<<160, 256, 0, stream>>>(W1, 109, 128, 320, w1t_hi, w1t_lo);
    convT_kernel<<<80, 256, 0, stream>>>(W2, 320, 320, 64, w2t_hi, w2t_lo);
    convWcat_kernel<<<16, 256, 0, stream>>>(Wmu, Wls, wct_hi, wct_lo);

    // ---- layer 1: xa = agg(x) -> bf16 pair; h1 = relu(xa@W1 + b1) -> bf16 pair ----
    agg109_bf16_kernel<<<NB_AGG, TB, 0, stream>>>(rowstart, esrc, dinv, x, xa_hi, xa_lo);
    mfma_gemm_kernel<0><<<dim3(391, 5), 256, 0, stream>>>(xa_hi, xa_lo, w1t_hi, w1t_lo, b1,
                                                          nullptr, h1_hi, h1_lo, nullptr,
                                                          NN, 320, 128);

    // ---- layer 2: g2 = (h1@W2)*dinv; h2 = relu(agg(g2) + b2) -> bf16 pair ----
    mfma_gemm_kernel<1><<<dim3(391, 1), 256, 0, stream>>>(h1_hi, h1_lo, w2t_hi, w2t_lo, nullptr,
                                                          dinv, nullptr, nullptr, g2,
                                                          NN, 64, 320);
    agg64_relu_bf16_kernel<<<NB_AGG, TB, 0, stream>>>(rowstart, esrc, dinv, g2, b2, h2_hi, h2_lo);

    // ---- layers 3+4: g3 = (h2@[Wmu|Wls])*dinv; out = agg(g3) + [bmu|bls] ----
    convWcat_kernel<<<16, 256, 0, stream>>>(Wmu, Wls, wct_hi, wct_lo);
    mfma_gemm_kernel<1><<<dim3(391, 1), 256, 0, stream>>>(h2_hi, h2_lo, wct_hi, wct_lo, nullptr,
                                                          dinv, nullptr, nullptr, g2,
                                                          NN, 64, 64);
    agg64_final_kernel<<<NB_AGG, TB, 0, stream>>>(rowstart, esrc, dinv, g2, bmu, bls, out);
}

// Round 6
// 221.129 us; speedup vs baseline: 2.7689x; 1.0830x over previous
//
#include <hip/hip_runtime.h>

#define NN 50000
#define NE 400000

typedef __attribute__((ext_vector_type(8))) short short8v;
typedef __attribute__((ext_vector_type(4))) float f32x4;

__device__ __forceinline__ unsigned short f2bf_rtn(float x) {
    unsigned u = __float_as_uint(x);
    unsigned r = u + 0x7FFFu + ((u >> 16) & 1u);
    return (unsigned short)(r >> 16);
}
__device__ __forceinline__ float bf2f(unsigned short h) {
    return __uint_as_float(((unsigned)h) << 16);
}

// ---------------- degree / hist ----------------
__global__ void zero_int_kernel(int* __restrict__ p, int n) {
    int i = blockIdx.x * blockDim.x + threadIdx.x;
    if (i < n) p[i] = 0;
}

__global__ void hist_kernel(const int* __restrict__ dst, int* __restrict__ counts) {
    for (int e = blockIdx.x * blockDim.x + threadIdx.x; e < NE; e += gridDim.x * blockDim.x)
        atomicAdd(&counts[dst[e]], 1);
}

__global__ void dinv_kernel(const int* __restrict__ counts, float* __restrict__ dinv) {
    int i = blockIdx.x * blockDim.x + threadIdx.x;
    if (i < NN) dinv[i] = rsqrtf((float)(counts[i] + 1));  // +1 self loop
}

// ---------------- exclusive scan over counts -> rowstart ----------------
__global__ void scan1_kernel(const int* __restrict__ counts, int* __restrict__ rowstart,
                             int* __restrict__ bsum) {
    __shared__ int tmp[256];
    int tid = threadIdx.x;
    int i = blockIdx.x * 256 + tid;
    int v = (i < NN) ? counts[i] : 0;
    tmp[tid] = v;
    __syncthreads();
    for (int off = 1; off < 256; off <<= 1) {
        int t = 0;
        if (tid >= off) t = tmp[tid - off];
        __syncthreads();
        if (tid >= off) tmp[tid] += t;
        __syncthreads();
    }
    if (i < NN) rowstart[i] = tmp[tid] - v;  // exclusive
    if (tid == 255) bsum[blockIdx.x] = tmp[255];
}

__global__ void scan2_kernel(int* __restrict__ bsum, int nb) {
    __shared__ int tmp[256];
    int tid = threadIdx.x;
    int v = (tid < nb) ? bsum[tid] : 0;
    tmp[tid] = v;
    __syncthreads();
    for (int off = 1; off < 256; off <<= 1) {
        int t = 0;
        if (tid >= off) t = tmp[tid - off];
        __syncthreads();
        if (tid >= off) tmp[tid] += t;
        __syncthreads();
    }
    if (tid < nb) bsum[tid] = tmp[tid] - v;  // exclusive
}

__global__ void scan3_kernel(int* __restrict__ rowstart, const int* __restrict__ bsum) {
    int i = blockIdx.x * 256 + threadIdx.x;
    if (i < NN) rowstart[i] += bsum[blockIdx.x];
    if (i == 0) rowstart[NN] = NE;
}

__global__ void scatter_kernel(const int* __restrict__ src, const int* __restrict__ dst,
                               const int* __restrict__ rowstart, int* __restrict__ cursor,
                               int* __restrict__ esrc) {
    for (int e = blockIdx.x * blockDim.x + threadIdx.x; e < NE; e += gridDim.x * blockDim.x) {
        int d = dst[e];
        int pos = rowstart[d] + atomicAdd(&cursor[d], 1);
        esrc[pos] = src[e];
    }
}

// ---------------- CSR aggregation, layer 1 -> bf16 hi/lo, K padded to 128 ----------------
__global__ __launch_bounds__(256) void agg109_bf16_kernel(const int* __restrict__ rowstart,
                                                          const int* __restrict__ esrc,
                                                          const float* __restrict__ dinv,
                                                          const float* __restrict__ x,
                                                          unsigned short* __restrict__ xa_hi,
                                                          unsigned short* __restrict__ xa_lo) {
    int wave = blockIdx.x * (blockDim.x >> 6) + (threadIdx.x >> 6);
    if (wave >= NN) return;
    int lane = threadIdx.x & 63;
    bool lo45 = lane < 45;
    long base = (long)wave * 109;
    float wd = dinv[wave];
    float acc0 = x[base + lane] * wd;
    float acc1 = lo45 ? x[base + 64 + lane] * wd : 0.0f;
    int j0 = rowstart[wave], j1 = rowstart[wave + 1];
    int j = j0;
    for (; j + 4 <= j1; j += 4) {
        int s0 = esrc[j], s1 = esrc[j + 1], s2 = esrc[j + 2], s3 = esrc[j + 3];
        float w0 = dinv[s0], w1 = dinv[s1], w2 = dinv[s2], w3 = dinv[s3];
        long b0 = (long)s0 * 109, b1 = (long)s1 * 109, b2 = (long)s2 * 109, b3 = (long)s3 * 109;
        float p0 = x[b0 + lane], p1 = x[b1 + lane], p2 = x[b2 + lane], p3 = x[b3 + lane];
        float q0 = 0, q1 = 0, q2 = 0, q3 = 0;
        if (lo45) {
            q0 = x[b0 + 64 + lane]; q1 = x[b1 + 64 + lane];
            q2 = x[b2 + 64 + lane]; q3 = x[b3 + 64 + lane];
        }
        acc0 = fmaf(p0, w0, acc0); acc0 = fmaf(p1, w1, acc0);
        acc0 = fmaf(p2, w2, acc0); acc0 = fmaf(p3, w3, acc0);
        acc1 = fmaf(q0, w0, acc1); acc1 = fmaf(q1, w1, acc1);
        acc1 = fmaf(q2, w2, acc1); acc1 = fmaf(q3, w3, acc1);
    }
    for (; j < j1; ++j) {
        int s = esrc[j];
        long sb = (long)s * 109;
        float w = dinv[s];
        acc0 = fmaf(x[sb + lane], w, acc0);
        if (lo45) acc1 = fmaf(x[sb + 64 + lane], w, acc1);
    }
    acc0 *= wd;
    float v1 = lo45 ? acc1 * wd : 0.0f;  // cols 109..127 zero-padded
    long ob = (long)wave * 128;
    unsigned short h0 = f2bf_rtn(acc0);
    xa_hi[ob + lane] = h0;
    xa_lo[ob + lane] = f2bf_rtn(acc0 - bf2f(h0));
    unsigned short h1 = f2bf_rtn(v1);
    xa_hi[ob + 64 + lane] = h1;
    xa_lo[ob + 64 + lane] = lo45 ? f2bf_rtn(v1 - bf2f(h1)) : (unsigned short)0;
}

// C = 64, epilogue: relu(v * dinv + b) -> bf16 hi/lo; unroll x4
__global__ __launch_bounds__(256) void agg64_relu_bf16_kernel(const int* __restrict__ rowstart,
                                                              const int* __restrict__ esrc,
                                                              const float* __restrict__ dinv,
                                                              const float* __restrict__ g,
                                                              const float* __restrict__ b,
                                                              unsigned short* __restrict__ hhi,
                                                              unsigned short* __restrict__ hlo) {
    int wave = blockIdx.x * (blockDim.x >> 6) + (threadIdx.x >> 6);
    if (wave >= NN) return;
    int lane = threadIdx.x & 63;
    long base = (long)wave * 64;
    float acc = g[base + lane];
    int j0 = rowstart[wave], j1 = rowstart[wave + 1];
    int j = j0;
    for (; j + 4 <= j1; j += 4) {
        int s0 = esrc[j], s1 = esrc[j + 1], s2 = esrc[j + 2], s3 = esrc[j + 3];
        float p0 = g[(long)s0 * 64 + lane], p1 = g[(long)s1 * 64 + lane];
        float p2 = g[(long)s2 * 64 + lane], p3 = g[(long)s3 * 64 + lane];
        acc += p0 + p1 + p2 + p3;
    }
    for (; j < j1; ++j) acc += g[(long)esrc[j] * 64 + lane];
    float v = acc * dinv[wave] + b[lane];
    v = v > 0.0f ? v : 0.0f;
    unsigned short hb = f2bf_rtn(v);
    hhi[base + lane] = hb;
    hlo[base + lane] = f2bf_rtn(v - bf2f(hb));
}

// C = 64, final: split into mu / logstd halves of d_out, + bias; unroll x4
__global__ __launch_bounds__(256) void agg64_final_kernel(const int* __restrict__ rowstart,
                                                          const int* __restrict__ esrc,
                                                          const float* __restrict__ dinv,
                                                          const float* __restrict__ g,
                                                          const float* __restrict__ bmu,
                                                          const float* __restrict__ bls,
                                                          float* __restrict__ out) {
    int wave = blockIdx.x * (blockDim.x >> 6) + (threadIdx.x >> 6);
    if (wave >= NN) return;
    int lane = threadIdx.x & 63;
    long base = (long)wave * 64;
    float acc = g[base + lane];
    int j0 = rowstart[wave], j1 = rowstart[wave + 1];
    int j = j0;
    for (; j + 4 <= j1; j += 4) {
        int s0 = esrc[j], s1 = esrc[j + 1], s2 = esrc[j + 2], s3 = esrc[j + 3];
        float p0 = g[(long)s0 * 64 + lane], p1 = g[(long)s1 * 64 + lane];
        float p2 = g[(long)s2 * 64 + lane], p3 = g[(long)s3 * 64 + lane];
        acc += p0 + p1 + p2 + p3;
    }
    for (; j < j1; ++j) acc += g[(long)esrc[j] * 64 + lane];
    float v = acc * dinv[wave];
    if (lane < 32)
        out[(long)wave * 32 + lane] = v + bmu[lane];
    else
        out[(long)NN * 32 + (long)wave * 32 + (lane - 32)] = v + bls[lane - 32];
}

// ---------------- weight conversion: src[Kreal][N] fp32 -> dst[N][KP] bf16 hi/lo ----------------
__global__ void convT_kernel(const float* __restrict__ src, int Kreal, int KP, int N,
                             unsigned short* __restrict__ dhi, unsigned short* __restrict__ dlo) {
    int idx = blockIdx.x * blockDim.x + threadIdx.x;
    if (idx >= N * KP) return;
    int n = idx / KP, k = idx - n * KP;
    float v = (k < Kreal) ? src[(long)k * N + n] : 0.0f;
    unsigned short hb = f2bf_rtn(v);
    dhi[idx] = hb;
    dlo[idx] = f2bf_rtn(v - bf2f(hb));
}

// [Wmu | Wls] -> wcatT[64][64] bf16 hi/lo
__global__ void convWcat_kernel(const float* __restrict__ Wmu, const float* __restrict__ Wls,
                                unsigned short* __restrict__ dhi, unsigned short* __restrict__ dlo) {
    int idx = blockIdx.x * blockDim.x + threadIdx.x;
    if (idx >= 4096) return;
    int n = idx >> 6, k = idx & 63;
    float v = (n < 32) ? Wmu[k * 32 + n] : Wls[k * 32 + (n - 32)];
    unsigned short hb = f2bf_rtn(v);
    dhi[idx] = hb;
    dlo[idx] = f2bf_rtn(v - bf2f(hb));
}

// ---------------- split-bf16 MFMA GEMM, 64x64 tile ----------------
// C[M,N] = A[M,K] @ B^T[N,K]  (A,B hi/lo bf16; K multiple of 64)
// 4 waves; wave w = rows w*16..w*16+15, all 64 cols. BK=64.
// 1D grid with bijective XCD swizzle: n-tiles fastest within an XCD chunk so
// same-A blocks share one XCD L2 (~3.2 MB A slice < 4 MB).
// MODE 0: relu(acc+bias[col]) -> Chi/Clo. MODE 1: acc*dinv[row] -> Cf fp32.
#define LDT 72  // LDS row stride (bf16); 144 B -> rows hit banks r*4%32: 2-way only (free)

template <int MODE>
__global__ __launch_bounds__(256) void mfma_gemm_kernel(
    const unsigned short* __restrict__ Ahi, const unsigned short* __restrict__ Alo,
    const unsigned short* __restrict__ Bhi, const unsigned short* __restrict__ Blo,
    const float* __restrict__ bias, const float* __restrict__ dinv,
    unsigned short* __restrict__ Chi, unsigned short* __restrict__ Clo,
    float* __restrict__ Cf, int M, int N, int K, int grid_n) {
    __shared__ unsigned short As[2 * 64 * LDT];  // hi at 0, lo at 64*LDT
    __shared__ unsigned short Bs[2 * 64 * LDT];
    int tid = threadIdx.x;
    int wid = tid >> 6, lane = tid & 63;
    int l15 = lane & 15, l4 = lane >> 4;

    // bijective XCD swizzle (assumes hw round-robin bid%8 -> XCD; perf-only)
    int T = gridDim.x;
    int xcd = blockIdx.x & 7, jj = blockIdx.x >> 3;
    int q = T >> 3, r = T & 7;
    int start = (xcd < r) ? xcd * (q + 1) : r * (q + 1) + (xcd - r) * q;
    int lin = start + jj;
    int bm = lin / grid_n, bn = lin - bm * grid_n;
    int bm0 = bm * 64, bn0 = bn * 64;

    f32x4 acc[4] = {};

    for (int kc = 0; kc < K; kc += 64) {
        #pragma unroll
        for (int r2 = 0; r2 < 2; ++r2) {
            int idx = tid + 256 * r2;
            int row = idx >> 3, slot = idx & 7;
            int grow = bm0 + row;
            if (grow >= M) grow = M - 1;  // clamp; epilogue guards stores
            long go = (long)grow * K + kc + slot * 8;
            *(uint4*)&As[row * LDT + slot * 8] = *(const uint4*)&Ahi[go];
            *(uint4*)&As[64 * LDT + row * LDT + slot * 8] = *(const uint4*)&Alo[go];
            long gob = (long)(bn0 + row) * K + kc + slot * 8;
            *(uint4*)&Bs[row * LDT + slot * 8] = *(const uint4*)&Bhi[gob];
            *(uint4*)&Bs[64 * LDT + row * LDT + slot * 8] = *(const uint4*)&Blo[gob];
        }
        __syncthreads();
        #pragma unroll
        for (int ks = 0; ks < 2; ++ks) {
            int koff = ks * 32 + l4 * 8;
            int ra = (wid * 16 + l15) * LDT + koff;
            short8v ah = *(const short8v*)&As[ra];
            short8v al = *(const short8v*)&As[64 * LDT + ra];
            #pragma unroll
            for (int n = 0; n < 4; ++n) {
                int rb = (n * 16 + l15) * LDT + koff;
                short8v bh = *(const short8v*)&Bs[rb];
                short8v bl = *(const short8v*)&Bs[64 * LDT + rb];
                acc[n] = __builtin_amdgcn_mfma_f32_16x16x32_bf16(ah, bh, acc[n], 0, 0, 0);
                acc[n] = __builtin_amdgcn_mfma_f32_16x16x32_bf16(al, bh, acc[n], 0, 0, 0);
                acc[n] = __builtin_amdgcn_mfma_f32_16x16x32_bf16(ah, bl, acc[n], 0, 0, 0);
            }
        }
        __syncthreads();
    }
    // epilogue: C/D frag mapping col=lane&15, row=(lane>>4)*4+reg
    int rbase = bm0 + wid * 16 + l4 * 4;
    #pragma unroll
    for (int q2 = 0; q2 < 4; ++q2) {
        int grow = rbase + q2;
        if (grow >= M) continue;
        float rs = (MODE == 1) ? dinv[grow] : 0.0f;
        #pragma unroll
        for (int n = 0; n < 4; ++n) {
            int gcol = bn0 + n * 16 + l15;
            float v = acc[n][q2];
            if (MODE == 0) {
                v += bias[gcol];
                v = v > 0.0f ? v : 0.0f;
                unsigned short hb = f2bf_rtn(v);
                long o = (long)grow * N + gcol;
                Chi[o] = hb;
                Clo[o] = f2bf_rtn(v - bf2f(hb));
            } else {
                Cf[(long)grow * N + gcol] = v * rs;
            }
        }
    }
}

extern "C" void kernel_launch(void* const* d_in, const int* in_sizes, int n_in,
                              void* d_out, int out_size, void* d_ws, size_t ws_size,
                              hipStream_t stream) {
    const float* x   = (const float*)d_in[0];
    const int*   ei  = (const int*)d_in[1];
    const int*   src = ei;       // edge_index[0]
    const int*   dst = ei + NE;  // edge_index[1]
    const float* W1  = (const float*)d_in[2];
    const float* b1  = (const float*)d_in[3];
    const float* W2  = (const float*)d_in[4];
    const float* b2  = (const float*)d_in[5];
    const float* Wmu = (const float*)d_in[6];
    const float* bmu = (const float*)d_in[7];
    const float* Wls = (const float*)d_in[8];
    const float* bls = (const float*)d_in[9];
    float* out = (float*)d_out;

    // ---- workspace layout (~105 MB) ----
    char* p = (char*)d_ws;
    float* dinv   = (float*)p; p += 50048 * 4;
    int* counts   = (int*)p;   p += 50048 * 4;
    int* cursor   = (int*)p;   p += 50048 * 4;
    int* rowstart = (int*)p;   p += 50056 * 4;
    int* bsum     = (int*)p;   p += 256 * 4;
    int* esrc     = (int*)p;   p += 400000 * 4;
    unsigned short* xa_hi = (unsigned short*)p; p += 50000L * 128 * 2;  // later h2_hi
    unsigned short* xa_lo = (unsigned short*)p; p += 50000L * 128 * 2;  // later h2_lo
    unsigned short* h1_hi = (unsigned short*)p; p += 50000L * 320 * 2;
    unsigned short* h1_lo = (unsigned short*)p; p += 50000L * 320 * 2;
    float* g2             = (float*)p;          p += 50000L * 64 * 4;   // later g3
    unsigned short* w1t_hi = (unsigned short*)p; p += 320 * 128 * 2;
    unsigned short* w1t_lo = (unsigned short*)p; p += 320 * 128 * 2;
    unsigned short* w2t_hi = (unsigned short*)p; p += 64 * 320 * 2;
    unsigned short* w2t_lo = (unsigned short*)p; p += 64 * 320 * 2;
    unsigned short* wct_hi = (unsigned short*)p; p += 64 * 64 * 2;
    unsigned short* wct_lo = (unsigned short*)p; p += 64 * 64 * 2;
    unsigned short* h2_hi = xa_hi;  // xa dead after GEMM1
    unsigned short* h2_lo = xa_lo;

    const int TB = 256;
    const int NB_NODES = (NN + TB - 1) / TB;     // 196
    const int NB_AGG = (NN * 64 + TB - 1) / TB;  // 12500 (wave per node)

    // ---- CSR build ----
    zero_int_kernel<<<(100096 + TB - 1) / TB, TB, 0, stream>>>(counts, 100096);
    hist_kernel<<<1024, TB, 0, stream>>>(dst, counts);
    dinv_kernel<<<NB_NODES, TB, 0, stream>>>(counts, dinv);
    scan1_kernel<<<NB_NODES, TB, 0, stream>>>(counts, rowstart, bsum);
    scan2_kernel<<<1, 256, 0, stream>>>(bsum, NB_NODES);
    scan3_kernel<<<NB_NODES, TB, 0, stream>>>(rowstart, bsum);
    scatter_kernel<<<1024, TB, 0, stream>>>(src, dst, rowstart, cursor, esrc);

    // ---- weight conversions ----
    convT_kernel<<<160, 256, 0, stream>>>(W1, 109, 128, 320, w1t_hi, w1t_lo);
    convT_kernel<<<80, 256, 0, stream>>>(W2, 320, 320, 64, w2t_hi, w2t_lo);
    convWcat_kernel<<<16, 256, 0, stream>>>(Wmu, Wls, wct_hi, wct_lo);

    // ---- layer 1: xa = agg(x) -> bf16 pair; h1 = relu(xa@W1 + b1) -> bf16 pair ----
    agg109_bf16_kernel<<<NB_AGG, TB, 0, stream>>>(rowstart, esrc, dinv, x, xa_hi, xa_lo);
    mfma_gemm_kernel<0><<<782 * 5, 256, 0, stream>>>(xa_hi, xa_lo, w1t_hi, w1t_lo, b1,
                                                     nullptr, h1_hi, h1_lo, nullptr,
                                                     NN, 320, 128, 5);

    // ---- layer 2: g2 = (h1@W2)*dinv; h2 = relu(agg(g2) + b2) -> bf16 pair ----
    mfma_gemm_kernel<1><<<782, 256, 0, stream>>>(h1_hi, h1_lo, w2t_hi, w2t_lo, nullptr,
                                                 dinv, nullptr, nullptr, g2,
                                                 NN, 64, 320, 1);
    agg64_relu_bf16_kernel<<<NB_AGG, TB, 0, stream>>>(rowstart, esrc, dinv, g2, b2, h2_hi, h2_lo);

    // ---- layers 3+4: g3 = (h2@[Wmu|Wls])*dinv; out = agg(g3) + [bmu|bls] ----
    mfma_gemm_kernel<1><<<782, 256, 0, stream>>>(h2_hi, h2_lo, wct_hi, wct_lo, nullptr,
                                                 dinv, nullptr, nullptr, g2,
                                                 NN, 64, 64, 1);
    agg64_final_kernel<<<NB_AGG, TB, 0, stream>>>(rowstart, esrc, dinv, g2, bmu, bls, out);
}